// Round 4
// baseline (115.190 us; speedup 1.0000x reference)
//
#include <hip/hip_runtime.h>
#include <hip/hip_cooperative_groups.h>
#include <math.h>

namespace cg = cooperative_groups;

#define MARGIN 1.0f
#define NT 256   // threads per block
#define TI 512   // i's per block (2 per thread)
#define TJ 256   // j's per LDS tile (== NT)

// Single fused cooperative kernel.
// Each block handles a (TI x TJ) pair tile. It recomputes the squared
// distances it needs locally (inputs are ~0.55 MB -> fully L2-resident, the
// ~44x read amplification costs <1 us at L2 BW). No sqrt: d_i < d_j iff
// d2_i < d2_j. Count is analytic B(B-1)/2 (fp ties contribute <=1e-6 rel
// error vs 2.4e-2 threshold). Plain-store partials + grid sync + block-0
// reduce: no atomics, no memset, deterministic.
__global__ __launch_bounds__(NT) void fused_kernel(
    const float* __restrict__ e,    // (B,)
    const float* __restrict__ pv,   // (B,P)
    const float* __restrict__ pt,   // (P,)
    float* __restrict__ psum,       // (gridDim.x,) scratch in ws
    float* __restrict__ out,        // (1,)
    int B, int P, int nj)
{
    __shared__ float2 sde[TJ];      // (d2_j, e_j)

    const int it = blockIdx.x / nj;
    const int jt = blockIdx.x % nj;

    // ---- squared distance helper (P=16 fast path) ----
    auto dist2 = [&](int row) -> float {
        float s = 0.f;
        if ((P & 3) == 0) {
            const float4* r = (const float4*)(pv + (size_t)row * P);
            const float4* t = (const float4*)pt;
            for (int p = 0; p < (P >> 2); ++p) {
                float4 v = r[p], g = t[p];
                float a = v.x - g.x, b = v.y - g.y, c = v.z - g.z, d = v.w - g.w;
                s = fmaf(a, a, s); s = fmaf(b, b, s);
                s = fmaf(c, c, s); s = fmaf(d, d, s);
            }
        } else {
            const float* r = pv + (size_t)row * P;
            for (int p = 0; p < P; ++p) {
                float d = r[p] - pt[p];
                s = fmaf(d, d, s);
            }
        }
        return s;
    };

    // stage j-tile: one j per thread
    {
        int j = jt * TJ + (int)threadIdx.x;
        float dj = -INFINITY, ej = 0.f;   // -inf: d2_i < d2_j never true
        if (j < B) { dj = dist2(j); ej = e[j]; }
        sde[threadIdx.x] = make_float2(dj, ej);
    }

    // own i's: 2 per thread
    int i0 = it * TI + (int)threadIdx.x;
    int i1 = i0 + NT;
    bool ok0 = (i0 < B), ok1 = (i1 < B);
    float d0 = ok0 ? dist2(i0) : INFINITY;   // +inf: never masked-in
    float a0 = ok0 ? (e[i0] + MARGIN) : 0.f;
    float d1 = ok1 ? dist2(i1) : INFINITY;
    float a1 = ok1 ? (e[i1] + MARGIN) : 0.f;

    __syncthreads();

    const float4* sde4 = (const float4*)sde;  // 2 j's per ds_read_b128
    float sum = 0.f;
    #pragma unroll 8
    for (int k = 0; k < TJ / 2; ++k) {
        float4 q = sde4[k];   // (d2_j0, e_j0, d2_j1, e_j1), broadcast read
        float w;
        w = (d0 < q.x) ? a0 : -INFINITY;  sum += fmaxf(w - q.y, 0.f);
        w = (d1 < q.x) ? a1 : -INFINITY;  sum += fmaxf(w - q.y, 0.f);
        w = (d0 < q.z) ? a0 : -INFINITY;  sum += fmaxf(w - q.w, 0.f);
        w = (d1 < q.z) ? a1 : -INFINITY;  sum += fmaxf(w - q.w, 0.f);
    }

    // wave shuffle reduction, then cross-wave via LDS
    for (int off = 32; off > 0; off >>= 1)
        sum += __shfl_down(sum, off, 64);
    __shared__ float ws_sum[NT / 64];
    int wave = threadIdx.x >> 6;
    int lane = threadIdx.x & 63;
    if (lane == 0) ws_sum[wave] = sum;
    __syncthreads();
    if (threadIdx.x == 0) {
        float bsum = 0.f;
        for (int w = 0; w < NT / 64; ++w) bsum += ws_sum[w];
        psum[blockIdx.x] = bsum;   // plain store: no init required
    }

    cg::this_grid().sync();

    // block 0: final reduce + divide
    if (blockIdx.x == 0) {
        int nblk = (int)gridDim.x;
        float s = 0.f;
        for (int k = threadIdx.x; k < nblk; k += NT) s += psum[k];
        for (int off = 32; off > 0; off >>= 1)
            s += __shfl_down(s, off, 64);
        __shared__ float fs[NT / 64];
        if (lane == 0) fs[wave] = s;
        __syncthreads();
        if (threadIdx.x == 0) {
            float tot = 0.f;
            for (int w = 0; w < NT / 64; ++w) tot += fs[w];
            double cnt = 0.5 * (double)B * ((double)B - 1.0);
            if (cnt < 1.0) cnt = 1.0;
            out[0] = (float)((double)tot / cnt);
        }
    }
}

extern "C" void kernel_launch(void* const* d_in, const int* in_sizes, int n_in,
                              void* d_out, int out_size, void* d_ws, size_t ws_size,
                              hipStream_t stream)
{
    const float* energies = (const float*)d_in[0];  // (B,1) flat
    const float* pv       = (const float*)d_in[1];  // (B,P)
    const float* pt       = (const float*)d_in[2];  // (P,)
    int B = in_sizes[0];
    int P = in_sizes[2];

    int ni = (B + TI - 1) / TI;
    int nj = (B + TJ - 1) / TJ;
    int nblk = ni * nj;

    float* psum = (float*)d_ws;
    float* out  = (float*)d_out;

    void* args[] = { (void*)&energies, (void*)&pv, (void*)&pt,
                     (void*)&psum, (void*)&out,
                     (void*)&B, (void*)&P, (void*)&nj };
    hipLaunchCooperativeKernel((void*)fused_kernel, dim3(nblk), dim3(NT),
                               args, 0, stream);
}

// Round 5
// 77.521 us; speedup vs baseline: 1.4859x; 1.4859x over previous
//
#include <hip/hip_runtime.h>
#include <math.h>

#define MARGIN 1.0f
#define NT 256   // threads per block
#define TI 512   // i's per pair-block (2 per thread)
#define TJ 256   // j's per LDS tile

// ---------------- Kernel A: per-row SQUARED distance + acc zeroing ----------
// d_i < d_j  <=>  d2_i < d2_j (sqrt is monotone) -> skip v_sqrt_f32.
// Also zeroes the global accumulator/counter (stream order guarantees it
// completes before pair_kernel) — saves a separate memset dispatch.
__global__ __launch_bounds__(NT) void dist_kernel(
    const float* __restrict__ pv,   // (B, P)
    const float* __restrict__ pt,   // (P,)
    float* __restrict__ dist2,      // (B,) squared distances
    float* __restrict__ acc,        // [0]=sum
    unsigned* __restrict__ counter, // blocks-done counter
    int B, int P)
{
    if (blockIdx.x == 0 && threadIdx.x == 0) {
        acc[0] = 0.f;
        *counter = 0u;
    }
    int i = blockIdx.x * NT + threadIdx.x;
    if (i >= B) return;
    float s = 0.f;
    if ((P & 3) == 0) {
        const float4* row = (const float4*)(pv + (size_t)i * P);
        const float4* tgt = (const float4*)pt;
        for (int p = 0; p < (P >> 2); ++p) {
            float4 v = row[p];
            float4 t = tgt[p];
            float d0 = v.x - t.x, d1 = v.y - t.y, d2 = v.z - t.z, d3 = v.w - t.w;
            s = fmaf(d0, d0, s); s = fmaf(d1, d1, s);
            s = fmaf(d2, d2, s); s = fmaf(d3, d3, s);
        }
    } else {
        const float* row = pv + (size_t)i * P;
        for (int p = 0; p < P; ++p) {
            float d = row[p] - pt[p];
            s = fmaf(d, d, s);
        }
    }
    dist2[i] = s;
}

// ---------------- Kernel B: all-pairs masked loss, fused finalize ----------
// count is analytic: B(B-1)/2 (fp ties contribute <=1e-6 relative error,
// threshold is 2.4e-2). Inner loop: 5 VALU instr / pair, LDS broadcast
// ds_read_b128 serves 4 pairs.
__global__ __launch_bounds__(NT) void pair_kernel(
    const float* __restrict__ e,     // (B,)
    const float* __restrict__ dist2, // (B,)
    float* __restrict__ acc,         // [0]=sum (zeroed by dist_kernel)
    unsigned* __restrict__ counter,  // zeroed by dist_kernel
    float* __restrict__ out,
    int B, int nj)
{
    __shared__ float2 sde[TJ];       // (d2_j, e_j) interleaved

    int it = blockIdx.x / nj;
    int jt = blockIdx.x % nj;

    // stage j-tile (TJ == NT: one element per thread)
    {
        int j = jt * TJ + (int)threadIdx.x;
        bool ok = (j < B);
        float dj = ok ? dist2[j] : -INFINITY;  // -inf: d2_i < d2_j never true
        float ej = ok ? e[j]     : 0.f;
        sde[threadIdx.x] = make_float2(dj, ej);
    }
    __syncthreads();

    int i0 = it * TI + (int)threadIdx.x;
    int i1 = i0 + NT;
    bool ok0 = (i0 < B), ok1 = (i1 < B);
    float d0 = ok0 ? dist2[i0] : INFINITY;     // +inf: never masked-in
    float a0 = ok0 ? (e[i0] + MARGIN) : 0.f;
    float d1 = ok1 ? dist2[i1] : INFINITY;
    float a1 = ok1 ? (e[i1] + MARGIN) : 0.f;

    const float4* sde4 = (const float4*)sde;   // 2 j's per ds_read_b128
    float sum = 0.f;
    #pragma unroll 8
    for (int k = 0; k < TJ / 2; ++k) {
        float4 q = sde4[k];   // (d2_j0, e_j0, d2_j1, e_j1), broadcast read
        float w;
        w = (d0 < q.x) ? a0 : -INFINITY;  sum += fmaxf(w - q.y, 0.f);
        w = (d1 < q.x) ? a1 : -INFINITY;  sum += fmaxf(w - q.y, 0.f);
        w = (d0 < q.z) ? a0 : -INFINITY;  sum += fmaxf(w - q.w, 0.f);
        w = (d1 < q.z) ? a1 : -INFINITY;  sum += fmaxf(w - q.w, 0.f);
    }

    // wave-level shuffle reduction, then cross-wave via LDS
    for (int off = 32; off > 0; off >>= 1)
        sum += __shfl_down(sum, off, 64);
    __shared__ float ws_sum[NT / 64];
    int wave = threadIdx.x >> 6;
    int lane = threadIdx.x & 63;
    if (lane == 0) ws_sum[wave] = sum;
    __syncthreads();

    if (threadIdx.x == 0) {
        float bsum = 0.f;
        for (int w = 0; w < NT / 64; ++w) bsum += ws_sum[w];
        atomicAdd(&acc[0], bsum);
        __threadfence();
        unsigned prev = atomicAdd(counter, 1u);
        if (prev == gridDim.x - 1) {
            // all other blocks' adds happened-before their counter bump
            float s = atomicAdd(&acc[0], 0.f);   // coherent read via atomic path
            double cnt = 0.5 * (double)B * ((double)B - 1.0);
            if (cnt < 1.0) cnt = 1.0;
            out[0] = (float)((double)s / cnt);
        }
    }
}

extern "C" void kernel_launch(void* const* d_in, const int* in_sizes, int n_in,
                              void* d_out, int out_size, void* d_ws, size_t ws_size,
                              hipStream_t stream)
{
    const float* energies = (const float*)d_in[0];  // (B,1) flat
    const float* pv       = (const float*)d_in[1];  // (B,P)
    const float* pt       = (const float*)d_in[2];  // (P,)
    int B = in_sizes[0];
    int P = in_sizes[2];

    // ws layout: [0..1] float acc, [2] uint counter, [4..] dist2 array
    float*    acc     = (float*)d_ws;
    unsigned* counter = (unsigned*)d_ws + 2;
    float*    dist2   = (float*)d_ws + 4;

    int ni = (B + TI - 1) / TI;
    int nj = (B + TJ - 1) / TJ;

    dist_kernel<<<(B + NT - 1) / NT, NT, 0, stream>>>(pv, pt, dist2, acc, counter, B, P);
    pair_kernel<<<ni * nj, NT, 0, stream>>>(energies, dist2, acc, counter,
                                            (float*)d_out, B, nj);
}